// Round 7
// baseline (606.422 us; speedup 1.0000x reference)
//
#include <hip/hip_runtime.h>
#include <hip/hip_bf16.h>

// LSTM: I=32, H=64, O=8, B=4096, T=256, fused single kernel.
// Round 7: BR=4, grid=1024, 4 blocks/CU (__launch_bounds__(256,4)).
// Rounds 1-6 all pinned at ~1750 cyc/step regardless of issue-work: the wall
// is the serial chain (barrier->ds_read->MFMA->act->write) exposed at only
// 2 waves/SIMD. Fix = 4 independent recurrence chains per SIMD, paying 2x
// MFMA redundancy (BR=4 in a 16-row tile, 4x mirror): MFMA pipe ~930
// cyc/SIMD/step becomes the designed wall (~99 us).
//  - mirror map fr = nlow>>2: D rows quad*4+q ALL hold batch row `quad`,
//    so acc[0] is the lane's cell (quad, jw): 1 cell/lane, no selects.
//  - Pade activations (no exp), bias in MFMA C-operand, truncating bf16 pack.
//  - x from global, chunked 4 steps (nx[8]=32 VGPRs to fit 128-reg budget).
//  - h double-buffered in LDS, ONE __syncthreads per step.

#define T_LEN 256
#define I_SZ  32
#define H_SZ  64
#define O_SZ  8
#define BR    4
#define HS    72   // h row stride in shorts

typedef __attribute__((ext_vector_type(8))) short short8;
typedef __attribute__((ext_vector_type(4))) float f32x4;

static __device__ __forceinline__ unsigned fbits(float f) {
    union { float f; unsigned u; } v; v.f = f; return v.u;
}
// two floats -> packed bf16x2 (truncation): elem0 = lo, elem1 = hi
static __device__ __forceinline__ unsigned pk2t(float lo, float hi) {
    return __builtin_amdgcn_perm(fbits(hi), fbits(lo), 0x07060302u);
}
static __device__ __forceinline__ short f2bf_rne(float f) {   // init-time only
    union { __hip_bfloat16 b; short s; } u;
    u.b = __float2bfloat16(f);
    return u.s;
}
// tanh Pade[5/4], clamped. |err| <~ 1.1e-3, den >= 945.
static __device__ __forceinline__ float tanh_p(float x) {
    float x2 = x * x;
    float n  = fmaf(x2 + 105.0f, x2, 945.0f);
    float d  = fmaf(fmaf(15.0f, x2, 420.0f), x2, 945.0f);
    float r  = (x * n) * __builtin_amdgcn_rcpf(d);
    return fminf(fmaxf(r, -1.0f), 1.0f);
}
// sigmoid via folded Pade. |err| <~ 5.5e-4, den >= 60480.
static __device__ __forceinline__ float sig_p(float x) {
    float x2 = x * x;
    float n  = fmaf(x2 + 420.0f, x2, 15120.0f);
    float d  = fmaf(fmaf(60.0f, x2, 6720.0f), x2, 60480.0f);
    float r  = fmaf(x * n, __builtin_amdgcn_rcpf(d), 0.5f);
    return fminf(fmaxf(r, 0.0f), 1.0f);
}

__global__ __launch_bounds__(256, 4)
void lstm_fused_kernel(const float* __restrict__ x,
                       const float* __restrict__ W_ih,
                       const float* __restrict__ W_hh,
                       const float* __restrict__ b_ih,
                       const float* __restrict__ b_hh,
                       const float* __restrict__ W_fc,
                       const float* __restrict__ b_fc,
                       float* __restrict__ out)
{
    __shared__ short hbuf[2][BR][HS];  // h double buffer, bf16, rows 0..3
    __shared__ float Hf[BR][64];

    const int tid  = threadIdx.x;
    const int wave = tid >> 6;
    const int lane = tid & 63;
    const int quad = lane >> 4;
    const int nlow = lane & 15;
    const int jw   = wave * 16 + nlow;   // gate-col this lane's tiles own
    const int b0   = blockIdx.x * BR;

    // Mirror row for A-reads: rows m=0..15 -> batch row m>>2 (each 4x).
    const int fr = nlow >> 2;
    // This lane's cell: batch row = quad, hidden col = jw; value in acc[0].

    // ---- B fragments (weights) once into registers.
    short8 bfrag[4][3];
    f32x4  biasf[4];
    for (int g = 0; g < 4; ++g) {
        const int col = g * 64 + jw;
        {
            const float* wr = W_ih + col * I_SZ + quad * 8;
            short8 f;
            #pragma unroll
            for (int e = 0; e < 8; ++e) f[e] = f2bf_rne(wr[e]);
            bfrag[g][0] = f;
        }
        #pragma unroll
        for (int kt = 1; kt < 3; ++kt) {
            const float* wr = W_hh + col * H_SZ + (kt - 1) * 32 + quad * 8;
            short8 f;
            #pragma unroll
            for (int e = 0; e < 8; ++e) f[e] = f2bf_rne(wr[e]);
            bfrag[g][kt] = f;
        }
        const float bg = b_ih[col] + b_hh[col];
        biasf[g] = (f32x4){bg, bg, bg, bg};
    }

    // ---- zero h buffers (h0 = 0)
    for (int q = tid; q < 2 * BR * HS; q += 256) ((short*)hbuf)[q] = (short)0;

    // ---- x chunk machinery: lane owns x[b0+fr][t][quad*8 .. +7].
    // (4-fold lane duplication within the wave; same cache lines -> free.)
    const float* xb = x + ((size_t)(b0 + fr) * T_LEN) * I_SZ + quad * 8;

    float4 nx[8];                         // next-chunk fp32 (4 steps x 8 floats)
    short8 sc[4];                         // current-chunk bf16 fragments
    #pragma unroll
    for (int s = 0; s < 4; ++s) {
        nx[2*s]   = *(const float4*)(xb + s * I_SZ);
        nx[2*s+1] = *(const float4*)(xb + s * I_SZ + 4);
    }
    #pragma unroll
    for (int s = 0; s < 4; ++s) {
        union { uint4 u; short8 v; } w;
        w.u.x = pk2t(nx[2*s].x,   nx[2*s].y);
        w.u.y = pk2t(nx[2*s].z,   nx[2*s].w);
        w.u.z = pk2t(nx[2*s+1].x, nx[2*s+1].y);
        w.u.w = pk2t(nx[2*s+1].z, nx[2*s+1].w);
        sc[s] = w.v;
    }

    // LDS addresses
    const short* rb[2] = { &hbuf[0][fr][quad * 8], &hbuf[1][fr][quad * 8] };
    short*       wb[2] = { &hbuf[0][quad][jw],     &hbuf[1][quad][jw] };

    float cc = 0.f, hh = 0.f;

    for (int ch = 0; ch < 64; ++ch) {
        #pragma unroll
        for (int tc = 0; tc < 4; ++tc) {
            const int t = ch * 4 + tc;

            __syncthreads();             // h_{t-1} (and at t=0 the zeroing) visible

            // h fragments: A[m][k = 32*kt + quad*8 + e], rows via fr
            const short* hr = rb[t & 1];
            short8 a1 = *(const short8*)(hr);        // h cols  0..31
            short8 a2 = *(const short8*)(hr + 32);   // h cols 32..63

            // issue next chunk's global loads early in the chunk
            if (tc == 0 && ch + 1 < 64) {
                const float* nxt = xb + (t + 4) * I_SZ;
                #pragma unroll
                for (int s = 0; s < 4; ++s) {
                    nx[2*s]   = *(const float4*)(nxt + s * I_SZ);
                    nx[2*s+1] = *(const float4*)(nxt + s * I_SZ + 4);
                }
            }

            const short8 ax = sc[tc];

            f32x4 acc[4];
            #pragma unroll
            for (int g = 0; g < 4; ++g) {
                f32x4 a = __builtin_amdgcn_mfma_f32_16x16x32_bf16(ax, bfrag[g][0], biasf[g], 0, 0, 0);
                a = __builtin_amdgcn_mfma_f32_16x16x32_bf16(a1, bfrag[g][1], a, 0, 0, 0);
                a = __builtin_amdgcn_mfma_f32_16x16x32_bf16(a2, bfrag[g][2], a, 0, 0, 0);
                acc[g] = a;
            }

            // convert next chunk once its loads landed (3 steps of cover)
            if (tc == 3 && ch + 1 < 64) {
                #pragma unroll
                for (int s = 0; s < 4; ++s) {
                    union { uint4 u; short8 v; } w;
                    w.u.x = pk2t(nx[2*s].x,   nx[2*s].y);
                    w.u.y = pk2t(nx[2*s].z,   nx[2*s].w);
                    w.u.z = pk2t(nx[2*s+1].x, nx[2*s+1].y);
                    w.u.w = pk2t(nx[2*s+1].z, nx[2*s+1].w);
                    sc[s] = w.v;
                }
            }

            // ---- cell update: 1 cell/lane = (batch quad, col jw) = acc[g][0].
            float iv = sig_p(acc[0][0]);
            float fv = sig_p(acc[1][0]);
            float gv = tanh_p(acc[2][0]);
            float ov = sig_p(acc[3][0]);
            cc = fmaf(fv, cc, iv * gv);
            hh = ov * tanh_p(cc);

            wb[(t + 1) & 1][0] = (short)((fbits(hh) + 0x8000u) >> 16);
        }
    }

    // ---- epilogue: out[b0+r][o] = h_T[r] . W_fc[o] + b_fc[o]  (fp32 h)
    Hf[quad][jw] = hh;
    __syncthreads();

    if (tid < BR * O_SZ) {               // 32 threads
        const int r = tid >> 3;
        const int o = tid & 7;
        const float* wf = W_fc + o * H_SZ;
        float acc = b_fc[o];
        #pragma unroll
        for (int jx = 0; jx < H_SZ; ++jx) acc += Hf[r][jx] * wf[jx];
        out[(size_t)(b0 + r) * O_SZ + o] = acc;
    }
}

extern "C" void kernel_launch(void* const* d_in, const int* in_sizes, int n_in,
                              void* d_out, int out_size, void* d_ws, size_t ws_size,
                              hipStream_t stream) {
    const float* x    = (const float*)d_in[0];
    const float* W_ih = (const float*)d_in[1];
    const float* W_hh = (const float*)d_in[2];
    const float* b_ih = (const float*)d_in[3];
    const float* b_hh = (const float*)d_in[4];
    const float* W_fc = (const float*)d_in[5];
    const float* b_fc = (const float*)d_in[6];
    float* out = (float*)d_out;

    const int B = 4096;
    lstm_fused_kernel<<<dim3(B / BR), dim3(256), 0, stream>>>(
        x, W_ih, W_hh, b_ih, b_hh, W_fc, b_fc, out);
}

// Round 8
// 363.409 us; speedup vs baseline: 1.6687x; 1.6687x over previous
//
#include <hip/hip_runtime.h>
#include <hip/hip_bf16.h>

// LSTM: I=32, H=64, O=8, B=4096, T=256, fused single kernel.
// Round 8: BR=4, grid=1024, 4 blocks/CU. Same occupancy plan as round 7 but
// SPILL-PROOFED: round 7's __launch_bounds__(256,4) made the backend cap
// VGPRs at 64 and spill ~50 regs (WRITE_SIZE 682 MB of scratch). Fixes:
//  - amdgpu_waves_per_eu(4,4): pin occupancy target = 4 waves/EU (128 VGPR
//    cap), allocator cannot aim at 8/EU and spill.
//  - biasf[4] f32x4 (16 regs) replaced by persistent zero f32x4 C-operand
//    (4 regs) + 4 scalar bias adds after MFMA (only acc[g][0] is consumed).
//  - footprint ~116 VGPR: bfrag 48 + nx/sc staging 48 + zero4/bias 8 + misc.
// Structure otherwise = round 7: mirror fr=nlow>>2 (acc[0] = own cell, no
// selects), Pade activations, x chunked 4 steps, h double-buffer LDS,
// one __syncthreads per step.

#define T_LEN 256
#define I_SZ  32
#define H_SZ  64
#define O_SZ  8
#define BR    4
#define HS    72   // h row stride in shorts

typedef __attribute__((ext_vector_type(8))) short short8;
typedef __attribute__((ext_vector_type(4))) float f32x4;

static __device__ __forceinline__ unsigned fbits(float f) {
    union { float f; unsigned u; } v; v.f = f; return v.u;
}
// two floats -> packed bf16x2 (truncation pack): elem0 = lo, elem1 = hi
static __device__ __forceinline__ unsigned pk2t(float lo, float hi) {
    return __builtin_amdgcn_perm(fbits(hi), fbits(lo), 0x07060302u);
}
static __device__ __forceinline__ short f2bf_rne(float f) {   // init-time only
    union { __hip_bfloat16 b; short s; } u;
    u.b = __float2bfloat16(f);
    return u.s;
}
// tanh Pade[5/4], clamped. |err| <~ 1.1e-3, den >= 945.
static __device__ __forceinline__ float tanh_p(float x) {
    float x2 = x * x;
    float n  = fmaf(x2 + 105.0f, x2, 945.0f);
    float d  = fmaf(fmaf(15.0f, x2, 420.0f), x2, 945.0f);
    float r  = (x * n) * __builtin_amdgcn_rcpf(d);
    return fminf(fmaxf(r, -1.0f), 1.0f);
}
// sigmoid via folded Pade. |err| <~ 5.5e-4, den >= 60480.
static __device__ __forceinline__ float sig_p(float x) {
    float x2 = x * x;
    float n  = fmaf(x2 + 420.0f, x2, 15120.0f);
    float d  = fmaf(fmaf(60.0f, x2, 6720.0f), x2, 60480.0f);
    float r  = fmaf(x * n, __builtin_amdgcn_rcpf(d), 0.5f);
    return fminf(fmaxf(r, 0.0f), 1.0f);
}

__global__ __launch_bounds__(256)
__attribute__((amdgpu_waves_per_eu(4, 4)))
void lstm_fused_kernel(const float* __restrict__ x,
                       const float* __restrict__ W_ih,
                       const float* __restrict__ W_hh,
                       const float* __restrict__ b_ih,
                       const float* __restrict__ b_hh,
                       const float* __restrict__ W_fc,
                       const float* __restrict__ b_fc,
                       float* __restrict__ out)
{
    __shared__ short hbuf[2][BR][HS];  // h double buffer, bf16, rows 0..3
    __shared__ float Hf[BR][64];

    const int tid  = threadIdx.x;
    const int wave = tid >> 6;
    const int lane = tid & 63;
    const int quad = lane >> 4;
    const int nlow = lane & 15;
    const int jw   = wave * 16 + nlow;   // gate-col this lane's tiles own
    const int b0   = blockIdx.x * BR;

    // Mirror row for A-reads: A row m holds batch row m>>2 (each 4x).
    const int fr = nlow >> 2;
    // Lane's cell: (batch row quad, hidden col jw); value = acc[g][0].

    // ---- B fragments (weights) once into registers. 48 VGPRs.
    short8 bfrag[4][3];
    float  biasg[4];
    for (int g = 0; g < 4; ++g) {
        const int col = g * 64 + jw;
        {
            const float* wr = W_ih + col * I_SZ + quad * 8;
            short8 f;
            #pragma unroll
            for (int e = 0; e < 8; ++e) f[e] = f2bf_rne(wr[e]);
            bfrag[g][0] = f;
        }
        #pragma unroll
        for (int kt = 1; kt < 3; ++kt) {
            const float* wr = W_hh + col * H_SZ + (kt - 1) * 32 + quad * 8;
            short8 f;
            #pragma unroll
            for (int e = 0; e < 8; ++e) f[e] = f2bf_rne(wr[e]);
            bfrag[g][kt] = f;
        }
        biasg[g] = b_ih[col] + b_hh[col];
    }

    // Persistent zero C-operand (4 VGPRs, never clobbered).
    const f32x4 zero4 = {0.f, 0.f, 0.f, 0.f};

    // ---- zero h buffers (h0 = 0)
    for (int q = tid; q < 2 * BR * HS; q += 256) ((short*)hbuf)[q] = (short)0;

    // ---- x chunk machinery: lane owns x[b0+fr][t][quad*8 .. +7].
    const float* xb = x + ((size_t)(b0 + fr) * T_LEN) * I_SZ + quad * 8;

    float4 nx[8];                         // next-chunk fp32 (4 steps x 8 floats)
    short8 sc[4];                         // current-chunk bf16 fragments
    #pragma unroll
    for (int s = 0; s < 4; ++s) {
        nx[2*s]   = *(const float4*)(xb + s * I_SZ);
        nx[2*s+1] = *(const float4*)(xb + s * I_SZ + 4);
    }
    #pragma unroll
    for (int s = 0; s < 4; ++s) {
        union { uint4 u; short8 v; } w;
        w.u.x = pk2t(nx[2*s].x,   nx[2*s].y);
        w.u.y = pk2t(nx[2*s].z,   nx[2*s].w);
        w.u.z = pk2t(nx[2*s+1].x, nx[2*s+1].y);
        w.u.w = pk2t(nx[2*s+1].z, nx[2*s+1].w);
        sc[s] = w.v;
    }

    // LDS addresses
    const short* rb[2] = { &hbuf[0][fr][quad * 8], &hbuf[1][fr][quad * 8] };
    short*       wb[2] = { &hbuf[0][quad][jw],     &hbuf[1][quad][jw] };

    float cc = 0.f, hh = 0.f;

    for (int ch = 0; ch < 64; ++ch) {
        #pragma unroll
        for (int tc = 0; tc < 4; ++tc) {
            const int t = ch * 4 + tc;

            __syncthreads();             // h_{t-1} (and at t=0 the zeroing) visible

            // h fragments: A[m][k = 32*kt + quad*8 + e], rows via fr
            const short* hr = rb[t & 1];
            short8 a1 = *(const short8*)(hr);        // h cols  0..31
            short8 a2 = *(const short8*)(hr + 32);   // h cols 32..63

            // issue next chunk's global loads early in the chunk
            if (tc == 0 && ch + 1 < 64) {
                const float* nxt = xb + (t + 4) * I_SZ;
                #pragma unroll
                for (int s = 0; s < 4; ++s) {
                    nx[2*s]   = *(const float4*)(nxt + s * I_SZ);
                    nx[2*s+1] = *(const float4*)(nxt + s * I_SZ + 4);
                }
            }

            const short8 ax = sc[tc];

            f32x4 acc[4];
            #pragma unroll
            for (int g = 0; g < 4; ++g) {
                f32x4 a = __builtin_amdgcn_mfma_f32_16x16x32_bf16(ax, bfrag[g][0], zero4, 0, 0, 0);
                a = __builtin_amdgcn_mfma_f32_16x16x32_bf16(a1, bfrag[g][1], a, 0, 0, 0);
                a = __builtin_amdgcn_mfma_f32_16x16x32_bf16(a2, bfrag[g][2], a, 0, 0, 0);
                acc[g] = a;
            }

            // convert next chunk once its loads landed (3 steps of cover)
            if (tc == 3 && ch + 1 < 64) {
                #pragma unroll
                for (int s = 0; s < 4; ++s) {
                    union { uint4 u; short8 v; } w;
                    w.u.x = pk2t(nx[2*s].x,   nx[2*s].y);
                    w.u.y = pk2t(nx[2*s].z,   nx[2*s].w);
                    w.u.z = pk2t(nx[2*s+1].x, nx[2*s+1].y);
                    w.u.w = pk2t(nx[2*s+1].z, nx[2*s+1].w);
                    sc[s] = w.v;
                }
            }

            // ---- cell update: 1 cell/lane = (batch quad, col jw) = acc[g][0].
            float iv = sig_p(acc[0][0] + biasg[0]);
            float fv = sig_p(acc[1][0] + biasg[1]);
            float gv = tanh_p(acc[2][0] + biasg[2]);
            float ov = sig_p(acc[3][0] + biasg[3]);
            cc = fmaf(fv, cc, iv * gv);
            hh = ov * tanh_p(cc);

            wb[(t + 1) & 1][0] = (short)((fbits(hh) + 0x8000u) >> 16);
        }
    }

    // ---- epilogue: out[b0+r][o] = h_T[r] . W_fc[o] + b_fc[o]  (fp32 h)
    Hf[quad][jw] = hh;
    __syncthreads();

    if (tid < BR * O_SZ) {               // 32 threads
        const int r = tid >> 3;
        const int o = tid & 7;
        const float* wf = W_fc + o * H_SZ;
        float acc = b_fc[o];
        #pragma unroll
        for (int jx = 0; jx < H_SZ; ++jx) acc += Hf[r][jx] * wf[jx];
        out[(size_t)(b0 + r) * O_SZ + o] = acc;
    }
}

extern "C" void kernel_launch(void* const* d_in, const int* in_sizes, int n_in,
                              void* d_out, int out_size, void* d_ws, size_t ws_size,
                              hipStream_t stream) {
    const float* x    = (const float*)d_in[0];
    const float* W_ih = (const float*)d_in[1];
    const float* W_hh = (const float*)d_in[2];
    const float* b_ih = (const float*)d_in[3];
    const float* b_hh = (const float*)d_in[4];
    const float* W_fc = (const float*)d_in[5];
    const float* b_fc = (const float*)d_in[6];
    float* out = (float*)d_out;

    const int B = 4096;
    lstm_fused_kernel<<<dim3(B / BR), dim3(256), 0, stream>>>(
        x, W_ih, W_hh, b_ih, b_hh, W_fc, b_fc, out);
}